// Round 1
// baseline (139.513 us; speedup 1.0000x reference)
//
#include <hip/hip_runtime.h>
#include <math.h>

#define EPS 1e-8f
#define NN 65536
#define MM 512
#define CC 512

// ws layout (float offsets)
#define WS_GATES 0       // 2048
#define WS_HNEW  2048    // 512
#define WS_ROUT  2560    // 518
#define WS_SCAL  3080    // 10: 0 beta, 1 g, 2-4 shift, 5 gamma, 6 nb, 7 mx, 8 Z, 9 Zp
#define WS_PMAX  3104    // 1024
#define WS_S     4128    // 65536
#define WS_P     69664   // 65536
#define WS_READ  135200  // 512

__device__ __forceinline__ float wave_sum(float v) {
    for (int o = 32; o > 0; o >>= 1) v += __shfl_xor(v, o);
    return v;
}
__device__ __forceinline__ float wave_max(float v) {
    for (int o = 32; o > 0; o >>= 1) v = fmaxf(v, __shfl_xor(v, o));
    return v;
}
__device__ __forceinline__ float sigm(float x) { return 1.f / (1.f + expf(-x)); }
__device__ __forceinline__ float softplusf(float x) {
    return x > 20.f ? x : log1pf(expf(x));
}

// K1: gates[o] = W_ih[o,:] . [x, prev_read] + b_ih[o] + W_hh[o,:] . h + b_hh[o]
__global__ __launch_bounds__(256) void k_gates(const float* __restrict__ x,
                                               const float* __restrict__ pr,
                                               const float* __restrict__ h,
                                               const float* __restrict__ W_ih,
                                               const float* __restrict__ b_ih,
                                               const float* __restrict__ W_hh,
                                               const float* __restrict__ b_hh,
                                               float* __restrict__ ws) {
    const int o = blockIdx.x, t = threadIdx.x;
    const float* wi = W_ih + (size_t)o * 768;
    const float* wh = W_hh + (size_t)o * 512;
    float acc = 0.f;
    for (int k = t; k < 768; k += 256) acc += wi[k] * (k < 256 ? x[k] : pr[k - 256]);
    for (int k = t; k < 512; k += 256) acc += wh[k] * h[k];
    acc = wave_sum(acc);
    __shared__ float sred[4];
    if ((t & 63) == 0) sred[t >> 6] = acc;
    __syncthreads();
    if (t == 0)
        ws[WS_GATES + o] = sred[0] + sred[1] + sred[2] + sred[3] + b_ih[o] + b_hh[o];
}

// K2: LSTM cell -> h_new
__global__ __launch_bounds__(512) void k_lstm(const float* __restrict__ c,
                                              float* __restrict__ ws) {
    const int j = threadIdx.x;
    float ig = ws[WS_GATES + j];
    float fg = ws[WS_GATES + 512 + j];
    float gg = ws[WS_GATES + 1024 + j];
    float og = ws[WS_GATES + 1536 + j];
    float cn = sigm(fg) * c[j] + sigm(ig) * tanhf(gg);
    ws[WS_HNEW + j] = sigm(og) * tanhf(cn);
}

// K3: r_out[o] = W_read[o,:] . h_new + b_read[o]   (518 blocks)
__global__ __launch_bounds__(256) void k_rout(const float* __restrict__ W_read,
                                              const float* __restrict__ b_read,
                                              float* __restrict__ ws) {
    const int o = blockIdx.x, t = threadIdx.x;
    const float* wr = W_read + (size_t)o * 512;
    float acc = 0.f;
    for (int k = t; k < 512; k += 256) acc += wr[k] * ws[WS_HNEW + k];
    acc = wave_sum(acc);
    __shared__ float sred[4];
    if ((t & 63) == 0) sred[t >> 6] = acc;
    __syncthreads();
    if (t == 0) ws[WS_ROUT + o] = sred[0] + sred[1] + sred[2] + sred[3] + b_read[o];
}

// K3b: head scalars: beta, g, shift softmax, gamma, nb = ||key+eps||
__global__ __launch_bounds__(512) void k_params(float* __restrict__ ws) {
    const int t = threadIdx.x;
    float d = ws[WS_ROUT + t] + EPS;
    float sq = wave_sum(d * d);
    __shared__ float sred[8];
    if ((t & 63) == 0) sred[t >> 6] = sq;
    __syncthreads();
    if (t == 0) {
        float s = 0.f;
        for (int i = 0; i < 8; ++i) s += sred[i];
        ws[WS_SCAL + 6] = fmaxf(sqrtf(s), EPS);
        ws[WS_SCAL + 0] = softplusf(ws[WS_ROUT + 512]);
        ws[WS_SCAL + 1] = sigm(ws[WS_ROUT + 513]);
        float a = ws[WS_ROUT + 514], b = ws[WS_ROUT + 515], cc2 = ws[WS_ROUT + 516];
        float m = fmaxf(a, fmaxf(b, cc2));
        float ea = expf(a - m), eb = expf(b - m), ec = expf(cc2 - m);
        float ss = ea + eb + ec;
        ws[WS_SCAL + 2] = ea / ss;
        ws[WS_SCAL + 3] = eb / ss;
        ws[WS_SCAL + 4] = ec / ss;
        ws[WS_SCAL + 5] = 1.f + softplusf(ws[WS_ROUT + 517]);
    }
}

// K4: s[n] = beta * cos(memory[n]+eps, key+eps); per-block max -> PMAX
__global__ __launch_bounds__(256) void k_cos(const float* __restrict__ mem,
                                             float* __restrict__ ws) {
    const int t = threadIdx.x, lane = t & 63, wv = t >> 6;
    const int gw = blockIdx.x * 4 + wv;  // 4096 waves total
    const float beta = ws[WS_SCAL + 0], nb = ws[WS_SCAL + 6];
    const float* key = ws + WS_ROUT;
    float4 ka = *(const float4*)(key + lane * 4);
    float4 kb = *(const float4*)(key + 256 + lane * 4);
    ka.x += EPS; ka.y += EPS; ka.z += EPS; ka.w += EPS;
    kb.x += EPS; kb.y += EPS; kb.z += EPS; kb.w += EPS;
    float* sp = ws + WS_S;
    float wmax = -1e30f;
    for (int n = gw; n < NN; n += 4096) {
        const float4 va = *(const float4*)(mem + (size_t)n * 512 + lane * 4);
        const float4 vb = *(const float4*)(mem + (size_t)n * 512 + 256 + lane * 4);
        float ax = va.x + EPS, ay = va.y + EPS, az = va.z + EPS, aw = va.w + EPS;
        float bx = vb.x + EPS, by = vb.y + EPS, bz = vb.z + EPS, bw = vb.w + EPS;
        float dot = ax * ka.x + ay * ka.y + az * ka.z + aw * ka.w +
                    bx * kb.x + by * kb.y + bz * kb.z + bw * kb.w;
        float sq = ax * ax + ay * ay + az * az + aw * aw +
                   bx * bx + by * by + bz * bz + bw * bw;
        dot = wave_sum(dot);
        sq = wave_sum(sq);
        float na = fmaxf(sqrtf(sq), EPS);
        float sv = beta * dot / (na * nb);
        if (lane == 0) sp[n] = sv;
        wmax = fmaxf(wmax, sv);
    }
    __shared__ float sm[4];
    if (lane == 0) sm[wv] = wmax;
    __syncthreads();
    if (t == 0)
        ws[WS_PMAX + blockIdx.x] = fmaxf(fmaxf(sm[0], sm[1]), fmaxf(sm[2], sm[3]));
}

// K5: mx = max(PMAX), Z = sum exp(s - mx); zero Zp and READ
__global__ __launch_bounds__(1024) void k_softstats(float* __restrict__ ws) {
    const int t = threadIdx.x, lane = t & 63, wv = t >> 6;
    __shared__ float sred[16];
    __shared__ float smx;
    float v = ws[WS_PMAX + t];
    v = wave_max(v);
    if (lane == 0) sred[wv] = v;
    __syncthreads();
    if (t == 0) {
        float m = sred[0];
        for (int i = 1; i < 16; ++i) m = fmaxf(m, sred[i]);
        smx = m;
    }
    __syncthreads();
    const float mx = smx;
    const float* sp = ws + WS_S;
    float z = 0.f;
    for (int i = t; i < NN; i += 1024) z += expf(sp[i] - mx);
    z = wave_sum(z);
    __syncthreads();
    if (lane == 0) sred[wv] = z;
    __syncthreads();
    if (t == 0) {
        float s = 0.f;
        for (int i = 0; i < 16; ++i) s += sred[i];
        ws[WS_SCAL + 7] = mx;
        ws[WS_SCAL + 8] = s;
        ws[WS_SCAL + 9] = 0.f;  // Zp accumulator
    }
    if (t < 512) ws[WS_READ + t] = 0.f;
}

// K6: p[n] = (shift-conv of w_interp)[n] ^ gamma ; Zp += block sum
__global__ __launch_bounds__(256) void k_power(const float* __restrict__ rs,
                                               float* __restrict__ ws) {
    const int n = blockIdx.x * 256 + threadIdx.x;
    const float g = ws[WS_SCAL + 1];
    const float mx = ws[WS_SCAL + 7];
    const float invZ = 1.f / ws[WS_SCAL + 8];
    const float s0 = ws[WS_SCAL + 2], s1 = ws[WS_SCAL + 3], s2 = ws[WS_SCAL + 4];
    const float gamma = ws[WS_SCAL + 5];
    const float* sp = ws + WS_S;
    auto wint = [&](int i) -> float {
        i &= (NN - 1);
        return g * rs[i] + (1.f - g) * expf(sp[i] - mx) * invZ;
    };
    float wsh = wint(n - 1) * s0 + wint(n) * s1 + wint(n + 1) * s2;
    float pv = powf(wsh, gamma);
    ws[WS_P + n] = pv;
    float bs = wave_sum(pv);
    __shared__ float sred[4];
    if ((threadIdx.x & 63) == 0) sred[threadIdx.x >> 6] = bs;
    __syncthreads();
    if (threadIdx.x == 0)
        atomicAdd(&ws[WS_SCAL + 9], sred[0] + sred[1] + sred[2] + sred[3]);
}

// K8: read[m] = sum_n (p[n]/(Zp+eps)) * memory[n][m]   (512 blocks)
__global__ __launch_bounds__(256) void k_read(const float* __restrict__ mem,
                                              float* __restrict__ ws) {
    const int t = threadIdx.x, half = t >> 7, l = t & 127;
    const int col = l * 4;
    const float invZp = 1.f / (ws[WS_SCAL + 9] + EPS);
    const float* pp = ws + WS_P;
    float4 acc = make_float4(0.f, 0.f, 0.f, 0.f);
    for (int n = blockIdx.x * 2 + half; n < NN; n += 1024) {
        float w = pp[n] * invZp;
        float4 v = *(const float4*)(mem + (size_t)n * 512 + col);
        acc.x += w * v.x; acc.y += w * v.y; acc.z += w * v.z; acc.w += w * v.w;
    }
    __shared__ float sm[512];
    if (half == 1) {
        sm[col + 0] = acc.x; sm[col + 1] = acc.y; sm[col + 2] = acc.z; sm[col + 3] = acc.w;
    }
    __syncthreads();
    if (half == 0) {
        atomicAdd(&ws[WS_READ + col + 0], acc.x + sm[col + 0]);
        atomicAdd(&ws[WS_READ + col + 1], acc.y + sm[col + 1]);
        atomicAdd(&ws[WS_READ + col + 2], acc.z + sm[col + 2]);
        atomicAdd(&ws[WS_READ + col + 3], acc.w + sm[col + 3]);
    }
}

// K9: out[o] = sigmoid(W_out[o,:] . [h_new, read] + b_out[o])
__global__ __launch_bounds__(256) void k_out(const float* __restrict__ W_out,
                                             const float* __restrict__ b_out,
                                             const float* __restrict__ ws,
                                             float* __restrict__ out) {
    const int o = blockIdx.x, t = threadIdx.x;
    const float* wo = W_out + (size_t)o * 1024;
    float acc = 0.f;
    for (int k = t; k < 1024; k += 256) {
        float v = (k < 512) ? ws[WS_HNEW + k] : ws[WS_READ + k - 512];
        acc += wo[k] * v;
    }
    acc = wave_sum(acc);
    __shared__ float sred[4];
    if ((t & 63) == 0) sred[t >> 6] = acc;
    __syncthreads();
    if (t == 0)
        out[o] = sigm(sred[0] + sred[1] + sred[2] + sred[3] + b_out[o]);
}

extern "C" void kernel_launch(void* const* d_in, const int* in_sizes, int n_in,
                              void* d_out, int out_size, void* d_ws, size_t ws_size,
                              hipStream_t stream) {
    const float* x          = (const float*)d_in[0];
    const float* memory     = (const float*)d_in[1];
    const float* prev_read  = (const float*)d_in[2];
    const float* h          = (const float*)d_in[3];
    const float* c          = (const float*)d_in[4];
    const float* read_state = (const float*)d_in[5];
    // d_in[6] write_state, d_in[13] W_write, d_in[14] b_write: dead code in reference
    const float* W_ih  = (const float*)d_in[7];
    const float* b_ih  = (const float*)d_in[8];
    const float* W_hh  = (const float*)d_in[9];
    const float* b_hh  = (const float*)d_in[10];
    const float* W_read = (const float*)d_in[11];
    const float* b_read = (const float*)d_in[12];
    const float* W_out  = (const float*)d_in[15];
    const float* b_out  = (const float*)d_in[16];
    float* ws  = (float*)d_ws;
    float* out = (float*)d_out;

    k_gates<<<2048, 256, 0, stream>>>(x, prev_read, h, W_ih, b_ih, W_hh, b_hh, ws);
    k_lstm<<<1, 512, 0, stream>>>(c, ws);
    k_rout<<<518, 256, 0, stream>>>(W_read, b_read, ws);
    k_params<<<1, 512, 0, stream>>>(ws);
    k_cos<<<1024, 256, 0, stream>>>(memory, ws);
    k_softstats<<<1, 1024, 0, stream>>>(ws);
    k_power<<<256, 256, 0, stream>>>(read_state, ws);
    k_read<<<512, 256, 0, stream>>>(memory, ws);
    k_out<<<256, 256, 0, stream>>>(W_out, b_out, ws, out);
}

// Round 2
// 90.243 us; speedup vs baseline: 1.5460x; 1.5460x over previous
//
#include <hip/hip_runtime.h>
#include <math.h>

#define EPS 1e-8f
#define NN 65536

// ws float offsets
#define WS_GATES 0       // 2048
#define WS_HNEW  2048    // 512
#define WS_ROUT  2560    // 518
#define WS_SCAL  3080    // 16: 0 mx, 1 Z, 2 g, 3 s0, 4 s1, 5 s2, 6 gamma
#define WS_PMAX  3104    // 2048
#define WS_PEXP  5152    // 2048
#define WS_S     7200    // 65536
#define WS_PSUM  72736   // 512
#define WS_PART  73248   // 512*512
#define WS_READ  335392  // 512

__device__ __forceinline__ float wave_sum(float v) {
    for (int o = 32; o > 0; o >>= 1) v += __shfl_xor(v, o);
    return v;
}
__device__ __forceinline__ float wave_max(float v) {
    for (int o = 32; o > 0; o >>= 1) v = fmaxf(v, __shfl_xor(v, o));
    return v;
}
__device__ __forceinline__ float sigm(float x) { return 1.f / (1.f + expf(-x)); }
__device__ __forceinline__ float softplusf(float x) {
    return x > 20.f ? x : log1pf(expf(x));
}
__device__ __forceinline__ float dot4(float4 a, float4 b) {
    return a.x * b.x + a.y * b.y + a.z * b.z + a.w * b.w;
}

// K1: gates[o] = W_ih[o,:].[x,pr] + b_ih[o] + W_hh[o,:].h + b_hh[o]
// wave-per-output: 512 blocks x 4 waves
__global__ __launch_bounds__(256) void k_gates(const float* __restrict__ x,
                                               const float* __restrict__ pr,
                                               const float* __restrict__ h,
                                               const float* __restrict__ W_ih,
                                               const float* __restrict__ b_ih,
                                               const float* __restrict__ W_hh,
                                               const float* __restrict__ b_hh,
                                               float* __restrict__ ws) {
    const int t = threadIdx.x, lane = t & 63, wv = t >> 6;
    const int o = blockIdx.x * 4 + wv;
    const float* wi = W_ih + (size_t)o * 768;
    const float* wh = W_hh + (size_t)o * 512;
    float acc = 0.f;
    acc += dot4(*(const float4*)(wi + lane * 4), *(const float4*)(x + lane * 4));
    acc += dot4(*(const float4*)(wi + 256 + lane * 4), *(const float4*)(pr + lane * 4));
    acc += dot4(*(const float4*)(wi + 512 + lane * 4), *(const float4*)(pr + 256 + lane * 4));
    acc += dot4(*(const float4*)(wh + lane * 4), *(const float4*)(h + lane * 4));
    acc += dot4(*(const float4*)(wh + 256 + lane * 4), *(const float4*)(h + 256 + lane * 4));
    acc = wave_sum(acc);
    if (lane == 0) ws[WS_GATES + o] = acc + b_ih[o] + b_hh[o];
}

// K2: h_new (recomputed per block, LDS) + r_out[o] = W_read[o,:].h_new + b_read[o]
// 130 blocks x 4 waves (520 >= 518)
__global__ __launch_bounds__(256) void k_hr(const float* __restrict__ c,
                                            const float* __restrict__ W_read,
                                            const float* __restrict__ b_read,
                                            float* __restrict__ ws) {
    __shared__ float sh[512];
    const int t = threadIdx.x;
    for (int j = t; j < 512; j += 256) {
        float ig = ws[WS_GATES + j];
        float fg = ws[WS_GATES + 512 + j];
        float gg = ws[WS_GATES + 1024 + j];
        float og = ws[WS_GATES + 1536 + j];
        float cn = sigm(fg) * c[j] + sigm(ig) * tanhf(gg);
        float hn = sigm(og) * tanhf(cn);
        sh[j] = hn;
        if (blockIdx.x == 0) ws[WS_HNEW + j] = hn;
    }
    __syncthreads();
    const int lane = t & 63, wv = t >> 6;
    const int o = blockIdx.x * 4 + wv;
    if (o >= 518) return;
    const float* wr = W_read + (size_t)o * 512;
    float acc = 0.f;
    acc += dot4(*(const float4*)(wr + lane * 4), *(const float4*)(sh + lane * 4));
    acc += dot4(*(const float4*)(wr + 256 + lane * 4), *(const float4*)(sh + 256 + lane * 4));
    acc = wave_sum(acc);
    if (lane == 0) ws[WS_ROUT + o] = acc + b_read[o];
}

// K3: s[n] = beta*cos(mem[n]+eps, key+eps); per-block online (max, expsum)
// 2048 blocks x 4 waves = 8192 waves, 8 rows/wave
__global__ __launch_bounds__(256) void k_cos(const float* __restrict__ mem,
                                             float* __restrict__ ws) {
    const int t = threadIdx.x, lane = t & 63, wv = t >> 6;
    const int gw = blockIdx.x * 4 + wv;
    const float* key = ws + WS_ROUT;
    float4 ka = *(const float4*)(key + lane * 4);
    float4 kb = *(const float4*)(key + 256 + lane * 4);
    ka.x += EPS; ka.y += EPS; ka.z += EPS; ka.w += EPS;
    kb.x += EPS; kb.y += EPS; kb.z += EPS; kb.w += EPS;
    float kq = wave_sum(dot4(ka, ka) + dot4(kb, kb));
    const float nb = fmaxf(sqrtf(kq), EPS);
    const float beta = softplusf(key[512]);
    float* sp = ws + WS_S;
    float m = -1e30f, e = 0.f;
    for (int n = gw; n < NN; n += 8192) {
        float4 va = *(const float4*)(mem + (size_t)n * 512 + lane * 4);
        float4 vb = *(const float4*)(mem + (size_t)n * 512 + 256 + lane * 4);
        va.x += EPS; va.y += EPS; va.z += EPS; va.w += EPS;
        vb.x += EPS; vb.y += EPS; vb.z += EPS; vb.w += EPS;
        float dot = wave_sum(dot4(va, ka) + dot4(vb, kb));
        float sq  = wave_sum(dot4(va, va) + dot4(vb, vb));
        float na = fmaxf(sqrtf(sq), EPS);
        float sv = beta * dot / (na * nb);
        if (lane == 0) sp[n] = sv;
        float nm = fmaxf(m, sv);
        e = e * expf(m - nm) + expf(sv - nm);
        m = nm;
    }
    __shared__ float sm[4], se[4];
    if (lane == 0) { sm[wv] = m; se[wv] = e; }
    __syncthreads();
    if (t == 0) {
        float M = fmaxf(fmaxf(sm[0], sm[1]), fmaxf(sm[2], sm[3]));
        float E = se[0] * expf(sm[0] - M) + se[1] * expf(sm[1] - M) +
                  se[2] * expf(sm[2] - M) + se[3] * expf(sm[3] - M);
        ws[WS_PMAX + blockIdx.x] = M;
        ws[WS_PEXP + blockIdx.x] = E;
    }
}

// K4: global mx, Z from 2048 block partials; head scalars g/shift/gamma
__global__ __launch_bounds__(1024) void k_stats(float* __restrict__ ws) {
    const int t = threadIdx.x, lane = t & 63, wv = t >> 6;
    __shared__ float sred[16];
    __shared__ float smx;
    float m1 = ws[WS_PMAX + t], m2 = ws[WS_PMAX + 1024 + t];
    float v = wave_max(fmaxf(m1, m2));
    if (lane == 0) sred[wv] = v;
    __syncthreads();
    if (t == 0) {
        float M = sred[0];
        for (int i = 1; i < 16; ++i) M = fmaxf(M, sred[i]);
        smx = M;
    }
    __syncthreads();
    const float mx = smx;
    float z = ws[WS_PEXP + t] * expf(m1 - mx) + ws[WS_PEXP + 1024 + t] * expf(m2 - mx);
    z = wave_sum(z);
    __syncthreads();
    if (lane == 0) sred[wv] = z;
    __syncthreads();
    if (t == 0) {
        float Z = 0.f;
        for (int i = 0; i < 16; ++i) Z += sred[i];
        ws[WS_SCAL + 0] = mx;
        ws[WS_SCAL + 1] = Z;
        ws[WS_SCAL + 2] = sigm(ws[WS_ROUT + 513]);
        float a = ws[WS_ROUT + 514], b = ws[WS_ROUT + 515], cc = ws[WS_ROUT + 516];
        float mm = fmaxf(a, fmaxf(b, cc));
        float ea = expf(a - mm), eb = expf(b - mm), ec = expf(cc - mm);
        float ss = ea + eb + ec;
        ws[WS_SCAL + 3] = ea / ss;
        ws[WS_SCAL + 4] = eb / ss;
        ws[WS_SCAL + 5] = ec / ss;
        ws[WS_SCAL + 6] = 1.f + softplusf(ws[WS_ROUT + 517]);
    }
}

// K5: per-block p (shift-conv ^ gamma) + partial column sums of p*mem
// 512 blocks x 256 threads; block b owns rows [b*128, b*128+128), thread owns 2 cols
__global__ __launch_bounds__(256) void k_read(const float* __restrict__ mem,
                                              const float* __restrict__ rs,
                                              float* __restrict__ ws) {
    const int b = blockIdx.x, t = threadIdx.x;
    const int start = b * 128;
    const float mx = ws[WS_SCAL + 0];
    const float invZ = 1.f / ws[WS_SCAL + 1];
    const float g = ws[WS_SCAL + 2];
    const float s0 = ws[WS_SCAL + 3], s1 = ws[WS_SCAL + 4], s2 = ws[WS_SCAL + 5];
    const float gamma = ws[WS_SCAL + 6];
    const float* sp = ws + WS_S;
    __shared__ float wi_l[130];
    __shared__ float pl[128];
    __shared__ float s2r[2];
    if (t < 130) {
        int i = (start - 1 + t) & (NN - 1);
        wi_l[t] = g * rs[i] + (1.f - g) * expf(sp[i] - mx) * invZ;
    }
    __syncthreads();
    if (t < 128) {
        float wsh = wi_l[t] * s0 + wi_l[t + 1] * s1 + wi_l[t + 2] * s2;
        pl[t] = powf(wsh, gamma);
    }
    __syncthreads();
    if (t < 128) {
        float v = wave_sum(pl[t]);
        if ((t & 63) == 0) s2r[t >> 6] = v;
    }
    __syncthreads();
    if (t == 0) ws[WS_PSUM + b] = s2r[0] + s2r[1];

    float2 acc = make_float2(0.f, 0.f);
    const float* colp = mem + (size_t)start * 512 + t * 2;
    #pragma unroll 8
    for (int r = 0; r < 128; ++r) {
        float w = pl[r];
        float2 v = *(const float2*)(colp + (size_t)r * 512);
        acc.x += w * v.x;
        acc.y += w * v.y;
    }
    *(float2*)(ws + WS_PART + (size_t)b * 512 + t * 2) = acc;
}

// K6: Zp = sum(PSUM); read[col] = sum_b partial[b][col] / (Zp+eps)
// 8 blocks x 64 threads
__global__ __launch_bounds__(64) void k_fin(float* __restrict__ ws) {
    const int t = threadIdx.x;
    float z = 0.f;
    for (int i = t; i < 512; i += 64) z += ws[WS_PSUM + i];
    z = wave_sum(z);
    const float invZp = 1.f / (z + EPS);
    const int col = blockIdx.x * 64 + t;
    float s = 0.f;
    #pragma unroll 8
    for (int b = 0; b < 512; ++b) s += ws[WS_PART + b * 512 + col];
    ws[WS_READ + col] = s * invZp;
}

// K7: out[o] = sigmoid(W_out[o,:].[h_new, read] + b_out[o]); 64 blocks x 4 waves
__global__ __launch_bounds__(256) void k_out(const float* __restrict__ W_out,
                                             const float* __restrict__ b_out,
                                             const float* __restrict__ ws,
                                             float* __restrict__ out) {
    const int t = threadIdx.x, lane = t & 63, wv = t >> 6;
    const int o = blockIdx.x * 4 + wv;
    const float* wo = W_out + (size_t)o * 1024;
    float acc = 0.f;
    acc += dot4(*(const float4*)(wo + lane * 4), *(const float4*)(ws + WS_HNEW + lane * 4));
    acc += dot4(*(const float4*)(wo + 256 + lane * 4), *(const float4*)(ws + WS_HNEW + 256 + lane * 4));
    acc += dot4(*(const float4*)(wo + 512 + lane * 4), *(const float4*)(ws + WS_READ + lane * 4));
    acc += dot4(*(const float4*)(wo + 768 + lane * 4), *(const float4*)(ws + WS_READ + 256 + lane * 4));
    acc = wave_sum(acc);
    if (lane == 0) out[o] = sigm(acc + b_out[o]);
}

extern "C" void kernel_launch(void* const* d_in, const int* in_sizes, int n_in,
                              void* d_out, int out_size, void* d_ws, size_t ws_size,
                              hipStream_t stream) {
    const float* x          = (const float*)d_in[0];
    const float* memory     = (const float*)d_in[1];
    const float* prev_read  = (const float*)d_in[2];
    const float* h          = (const float*)d_in[3];
    const float* c          = (const float*)d_in[4];
    const float* read_state = (const float*)d_in[5];
    // d_in[6] write_state, d_in[13] W_write, d_in[14] b_write: dead in reference
    const float* W_ih   = (const float*)d_in[7];
    const float* b_ih   = (const float*)d_in[8];
    const float* W_hh   = (const float*)d_in[9];
    const float* b_hh   = (const float*)d_in[10];
    const float* W_read = (const float*)d_in[11];
    const float* b_read = (const float*)d_in[12];
    const float* W_out  = (const float*)d_in[15];
    const float* b_out  = (const float*)d_in[16];
    float* ws  = (float*)d_ws;
    float* out = (float*)d_out;

    k_gates<<<512, 256, 0, stream>>>(x, prev_read, h, W_ih, b_ih, W_hh, b_hh, ws);
    k_hr<<<130, 256, 0, stream>>>(c, W_read, b_read, ws);
    k_cos<<<2048, 256, 0, stream>>>(memory, ws);
    k_stats<<<1, 1024, 0, stream>>>(ws);
    k_read<<<512, 256, 0, stream>>>(memory, read_state, ws);
    k_fin<<<8, 64, 0, stream>>>(ws);
    k_out<<<64, 256, 0, stream>>>(W_out, b_out, ws, out);
}

// Round 3
// 76.997 us; speedup vs baseline: 1.8119x; 1.1720x over previous
//
#include <hip/hip_runtime.h>
#include <math.h>

#define EPS 1e-8f
#define NN 65536

// ws float offsets
#define WS_GATES 0       // 2048
#define WS_HNEW  2048    // 512
#define WS_ROUT  2560    // 518
#define WS_PMAX  3104    // 2048
#define WS_PEXP  5152    // 2048
#define WS_S     7200    // 65536
#define WS_PSUM  72736   // 256
#define WS_PART  72992   // 256*512
#define WS_END   204064  // ~816 KB

__device__ __forceinline__ float wave_sum(float v) {
    for (int o = 32; o > 0; o >>= 1) v += __shfl_xor(v, o);
    return v;
}
__device__ __forceinline__ float sigm(float x) { return 1.f / (1.f + expf(-x)); }
__device__ __forceinline__ float softplusf(float x) {
    return x > 20.f ? x : log1pf(expf(x));
}
__device__ __forceinline__ float dot4(float4 a, float4 b) {
    return a.x * b.x + a.y * b.y + a.z * b.z + a.w * b.w;
}

// K1: gates[o] = W_ih[o,:].[x,pr] + b_ih[o] + W_hh[o,:].h + b_hh[o]
// wave-per-output: 512 blocks x 4 waves
__global__ __launch_bounds__(256) void k_gates(const float* __restrict__ x,
                                               const float* __restrict__ pr,
                                               const float* __restrict__ h,
                                               const float* __restrict__ W_ih,
                                               const float* __restrict__ b_ih,
                                               const float* __restrict__ W_hh,
                                               const float* __restrict__ b_hh,
                                               float* __restrict__ ws) {
    const int t = threadIdx.x, lane = t & 63, wv = t >> 6;
    const int o = blockIdx.x * 4 + wv;
    const float* wi = W_ih + (size_t)o * 768;
    const float* wh = W_hh + (size_t)o * 512;
    float acc = 0.f;
    acc += dot4(*(const float4*)(wi + lane * 4), *(const float4*)(x + lane * 4));
    acc += dot4(*(const float4*)(wi + 256 + lane * 4), *(const float4*)(pr + lane * 4));
    acc += dot4(*(const float4*)(wi + 512 + lane * 4), *(const float4*)(pr + 256 + lane * 4));
    acc += dot4(*(const float4*)(wh + lane * 4), *(const float4*)(h + lane * 4));
    acc += dot4(*(const float4*)(wh + 256 + lane * 4), *(const float4*)(h + 256 + lane * 4));
    acc = wave_sum(acc);
    if (lane == 0) ws[WS_GATES + o] = acc + b_ih[o] + b_hh[o];
}

// K2: h_new (recomputed per block in LDS) + r_out[o] = W_read[o,:].h_new + b_read[o]
__global__ __launch_bounds__(256) void k_hr(const float* __restrict__ c,
                                            const float* __restrict__ W_read,
                                            const float* __restrict__ b_read,
                                            float* __restrict__ ws) {
    __shared__ float sh[512];
    const int t = threadIdx.x;
    for (int j = t; j < 512; j += 256) {
        float ig = ws[WS_GATES + j];
        float fg = ws[WS_GATES + 512 + j];
        float gg = ws[WS_GATES + 1024 + j];
        float og = ws[WS_GATES + 1536 + j];
        float cn = sigm(fg) * c[j] + sigm(ig) * tanhf(gg);
        float hn = sigm(og) * tanhf(cn);
        sh[j] = hn;
        if (blockIdx.x == 0) ws[WS_HNEW + j] = hn;
    }
    __syncthreads();
    const int lane = t & 63, wv = t >> 6;
    const int o = blockIdx.x * 4 + wv;
    if (o >= 518) return;
    const float* wr = W_read + (size_t)o * 512;
    float acc = 0.f;
    acc += dot4(*(const float4*)(wr + lane * 4), *(const float4*)(sh + lane * 4));
    acc += dot4(*(const float4*)(wr + 256 + lane * 4), *(const float4*)(sh + 256 + lane * 4));
    acc = wave_sum(acc);
    if (lane == 0) ws[WS_ROUT + o] = acc + b_read[o];
}

// K3: s[n] = beta*cos(mem[n]+eps, key+eps); per-block online (max, expsum)
// 2048 blocks x 4 waves = 8192 waves, 8 rows/wave
__global__ __launch_bounds__(256) void k_cos(const float* __restrict__ mem,
                                             float* __restrict__ ws) {
    const int t = threadIdx.x, lane = t & 63, wv = t >> 6;
    const int gw = blockIdx.x * 4 + wv;
    const float* key = ws + WS_ROUT;
    float4 ka = *(const float4*)(key + lane * 4);
    float4 kb = *(const float4*)(key + 256 + lane * 4);
    ka.x += EPS; ka.y += EPS; ka.z += EPS; ka.w += EPS;
    kb.x += EPS; kb.y += EPS; kb.z += EPS; kb.w += EPS;
    float kq = wave_sum(dot4(ka, ka) + dot4(kb, kb));
    const float nb = fmaxf(sqrtf(kq), EPS);
    const float beta = softplusf(key[512]);
    float* sp = ws + WS_S;
    float m = -1e30f, e = 0.f;
    for (int n = gw; n < NN; n += 8192) {
        float4 va = *(const float4*)(mem + (size_t)n * 512 + lane * 4);
        float4 vb = *(const float4*)(mem + (size_t)n * 512 + 256 + lane * 4);
        va.x += EPS; va.y += EPS; va.z += EPS; va.w += EPS;
        vb.x += EPS; vb.y += EPS; vb.z += EPS; vb.w += EPS;
        float dot = wave_sum(dot4(va, ka) + dot4(vb, kb));
        float sq  = wave_sum(dot4(va, va) + dot4(vb, vb));
        float na = fmaxf(sqrtf(sq), EPS);
        float sv = beta * dot / (na * nb);
        if (lane == 0) sp[n] = sv;
        float nm = fmaxf(m, sv);
        e = e * expf(m - nm) + expf(sv - nm);
        m = nm;
    }
    __shared__ float sm[4], se[4];
    if (lane == 0) { sm[wv] = m; se[wv] = e; }
    __syncthreads();
    if (t == 0) {
        float M = fmaxf(fmaxf(sm[0], sm[1]), fmaxf(sm[2], sm[3]));
        float E = se[0] * expf(sm[0] - M) + se[1] * expf(sm[1] - M) +
                  se[2] * expf(sm[2] - M) + se[3] * expf(sm[3] - M);
        ws[WS_PMAX + blockIdx.x] = M;
        ws[WS_PEXP + blockIdx.x] = E;
    }
}

// K4: fused stats + p + partial column sums. 256 blocks x 512 threads,
// block owns 256 rows; thread t: col4=(t&127)*4, row-quarter rq=t>>7.
__global__ __launch_bounds__(512) void k_read(const float* __restrict__ mem,
                                              const float* __restrict__ rs,
                                              float* __restrict__ ws) {
    const int b = blockIdx.x, t = threadIdx.x;
    const int lane = t & 63, wv = t >> 6;
    __shared__ float s_m[8], s_e[8];
    __shared__ float wi_l[258];
    __shared__ float pl[256];
    __shared__ float s_ps[4];
    __shared__ float4 sacc[3][128];

    // --- redundant global softmax stats from 2048 (max, expsum) partials ---
    float m = -1e30f, e = 0.f;
    for (int i = t; i < 2048; i += 512) {
        float bm = ws[WS_PMAX + i], be = ws[WS_PEXP + i];
        float nm = fmaxf(m, bm);
        e = e * expf(m - nm) + be * expf(bm - nm);
        m = nm;
    }
    for (int o = 32; o > 0; o >>= 1) {
        float om = __shfl_xor(m, o), oe = __shfl_xor(e, o);
        float nm = fmaxf(m, om);
        e = e * expf(m - nm) + oe * expf(om - nm);
        m = nm;
    }
    if (lane == 0) { s_m[wv] = m; s_e[wv] = e; }
    __syncthreads();
    float mx = s_m[0];
    for (int i = 1; i < 8; ++i) mx = fmaxf(mx, s_m[i]);
    float Z = 0.f;
    for (int i = 0; i < 8; ++i) Z += s_e[i] * expf(s_m[i] - mx);
    const float invZ = 1.f / Z;
    // --- head scalars (redundant per thread, deterministic) ---
    const float g = sigm(ws[WS_ROUT + 513]);
    float a3 = ws[WS_ROUT + 514], b3 = ws[WS_ROUT + 515], c3 = ws[WS_ROUT + 516];
    float mm = fmaxf(a3, fmaxf(b3, c3));
    float ea = expf(a3 - mm), eb = expf(b3 - mm), ec = expf(c3 - mm);
    float ss = ea + eb + ec;
    const float s0 = ea / ss, s1 = eb / ss, s2 = ec / ss;
    const float gamma = 1.f + softplusf(ws[WS_ROUT + 517]);

    // --- p for rows [b*256, b*256+256) ---
    const int start = b * 256;
    const float* sp = ws + WS_S;
    if (t < 258) {
        int idx = (start - 1 + t) & (NN - 1);
        wi_l[t] = g * rs[idx] + (1.f - g) * expf(sp[idx] - mx) * invZ;
    }
    __syncthreads();
    float ps = 0.f;
    if (t < 256) {
        float wsh = wi_l[t] * s0 + wi_l[t + 1] * s1 + wi_l[t + 2] * s2;
        float pv = powf(wsh, gamma);
        pl[t] = pv;
        ps = pv;
    }
    ps = wave_sum(ps);
    if (t < 256 && lane == 0) s_ps[wv] = ps;
    __syncthreads();
    if (t == 0) ws[WS_PSUM + b] = s_ps[0] + s_ps[1] + s_ps[2] + s_ps[3];

    // --- partial column sums: acc over 64 rows (stride 4) of float4 ---
    const int col = (t & 127) * 4;
    const int rq = t >> 7;
    float4 acc = make_float4(0.f, 0.f, 0.f, 0.f);
    const float* basep = mem + (size_t)start * 512 + col;
    #pragma unroll 8
    for (int r = rq; r < 256; r += 4) {
        float w = pl[r];
        float4 v = *(const float4*)(basep + (size_t)r * 512);
        acc.x += w * v.x; acc.y += w * v.y; acc.z += w * v.z; acc.w += w * v.w;
    }
    if (rq > 0) sacc[rq - 1][t & 127] = acc;
    __syncthreads();
    if (rq == 0) {
        float4 a0 = sacc[0][t & 127], a1 = sacc[1][t & 127], a2 = sacc[2][t & 127];
        acc.x += a0.x + a1.x + a2.x;
        acc.y += a0.y + a1.y + a2.y;
        acc.z += a0.z + a1.z + a2.z;
        acc.w += a0.w + a1.w + a2.w;
        *(float4*)(ws + WS_PART + (size_t)b * 512 + col) = acc;
    }
}

// K5: fused final reduce + output. 64 blocks x 256 threads (wave per output).
__global__ __launch_bounds__(256) void k_out(const float* __restrict__ W_out,
                                             const float* __restrict__ b_out,
                                             const float* __restrict__ ws,
                                             float* __restrict__ out) {
    const int t = threadIdx.x, lane = t & 63, wv = t >> 6;
    __shared__ float rd[512];
    __shared__ float s_z[4];
    float z = (t < 256) ? ws[WS_PSUM + t] : 0.f;
    z = wave_sum(z);
    if (lane == 0) s_z[wv] = z;
    float2 acc = make_float2(0.f, 0.f);
    const float* pp = ws + WS_PART + t * 2;
    #pragma unroll 16
    for (int r = 0; r < 256; ++r) {
        float2 v = *(const float2*)(pp + (size_t)r * 512);
        acc.x += v.x; acc.y += v.y;
    }
    __syncthreads();
    const float Zp = s_z[0] + s_z[1] + s_z[2] + s_z[3];
    const float invZp = 1.f / (Zp + EPS);
    rd[2 * t] = acc.x * invZp;
    rd[2 * t + 1] = acc.y * invZp;
    __syncthreads();
    const int o = blockIdx.x * 4 + wv;
    const float* wo = W_out + (size_t)o * 1024;
    float a = 0.f;
    a += dot4(*(const float4*)(wo + lane * 4), *(const float4*)(ws + WS_HNEW + lane * 4));
    a += dot4(*(const float4*)(wo + 256 + lane * 4), *(const float4*)(ws + WS_HNEW + 256 + lane * 4));
    a += dot4(*(const float4*)(wo + 512 + lane * 4), *(const float4*)(rd + lane * 4));
    a += dot4(*(const float4*)(wo + 768 + lane * 4), *(const float4*)(rd + 256 + lane * 4));
    a = wave_sum(a);
    if (lane == 0) out[o] = sigm(a + b_out[o]);
}

extern "C" void kernel_launch(void* const* d_in, const int* in_sizes, int n_in,
                              void* d_out, int out_size, void* d_ws, size_t ws_size,
                              hipStream_t stream) {
    const float* x          = (const float*)d_in[0];
    const float* memory     = (const float*)d_in[1];
    const float* prev_read  = (const float*)d_in[2];
    const float* h          = (const float*)d_in[3];
    const float* c          = (const float*)d_in[4];
    const float* read_state = (const float*)d_in[5];
    // d_in[6] write_state, d_in[13] W_write, d_in[14] b_write: dead in reference
    const float* W_ih   = (const float*)d_in[7];
    const float* b_ih   = (const float*)d_in[8];
    const float* W_hh   = (const float*)d_in[9];
    const float* b_hh   = (const float*)d_in[10];
    const float* W_read = (const float*)d_in[11];
    const float* b_read = (const float*)d_in[12];
    const float* W_out  = (const float*)d_in[15];
    const float* b_out  = (const float*)d_in[16];
    float* ws  = (float*)d_ws;
    float* out = (float*)d_out;

    k_gates<<<512, 256, 0, stream>>>(x, prev_read, h, W_ih, b_ih, W_hh, b_hh, ws);
    k_hr<<<130, 256, 0, stream>>>(c, W_read, b_read, ws);
    k_cos<<<2048, 256, 0, stream>>>(memory, ws);
    k_read<<<256, 512, 0, stream>>>(memory, read_state, ws);
    k_out<<<64, 256, 0, stream>>>(W_out, b_out, ws, out);
}